// Round 1
// baseline (1839.322 us; speedup 1.0000x reference)
//
#include <hip/hip_runtime.h>

// SGC: out = A_hat^2 (x W^T) + b, with A_hat = D^-1/2 (A+I) D^-1/2.
// GEMM-first (commutes), bias folded into hop-2 self-loop init.
//
// ws layout (floats):
//   [0, N)            dinv   (also used as deg accumulator)
//   [N, N+E)          norm   (per-edge dinv[src]*dinv[dst])
//   [N+E, N+E+N*64)   h1     (hop-1 output)
// d_out doubles as h0 = x W^T (dead after hop-1 reads it), then holds final out.

#define DF 64   // feature dim

__global__ __launch_bounds__(256) void deg_init(float* deg, int n) {
    int i = blockIdx.x * blockDim.x + threadIdx.x;
    if (i < n) deg[i] = 1.0f;  // self-loop
}

__global__ __launch_bounds__(256) void deg_scatter(const int* __restrict__ dst,
                                                   float* deg, int ne) {
    int e = blockIdx.x * blockDim.x + threadIdx.x;
    if (e < ne) atomicAdd(&deg[dst[e]], 1.0f);
}

__global__ __launch_bounds__(256) void dinv_k(float* deg, int n) {
    int i = blockIdx.x * blockDim.x + threadIdx.x;
    if (i < n) {
        float d = deg[i];
        deg[i] = d > 0.0f ? rsqrtf(d) : 0.0f;  // deg >= 1 always, keep ref semantics
    }
}

__global__ __launch_bounds__(256) void norm_k(const int* __restrict__ src,
                                              const int* __restrict__ dst,
                                              const float* __restrict__ dinv,
                                              float* __restrict__ norm, int ne) {
    int e = blockIdx.x * blockDim.x + threadIdx.x;
    if (e < ne) norm[e] = dinv[src[e]] * dinv[dst[e]];
}

// h0[r][j] = sum_k x[r][k] * W[j][k]   (no bias)
// wave per row; lane j holds W[j][:] in 64 regs; x value broadcast via readlane.
__global__ __launch_bounds__(256) void gemm_xw(const float* __restrict__ x,
                                               const float* __restrict__ Wm,
                                               float* __restrict__ h0, int nrows) {
    int lane = threadIdx.x & 63;
    int wave = (blockIdx.x * blockDim.x + threadIdx.x) >> 6;
    int nwaves = (gridDim.x * blockDim.x) >> 6;

    float w[DF];
#pragma unroll
    for (int k = 0; k < DF; ++k) w[k] = Wm[lane * DF + k];  // L2-resident, once per wave

    for (int r = wave; r < nrows; r += nwaves) {
        float hv = x[r * DF + lane];  // coalesced
        float a0 = 0.f, a1 = 0.f, a2 = 0.f, a3 = 0.f;
#pragma unroll
        for (int k = 0; k < DF; k += 4) {
            float x0 = __uint_as_float(__builtin_amdgcn_readlane(__float_as_uint(hv), k + 0));
            float x1 = __uint_as_float(__builtin_amdgcn_readlane(__float_as_uint(hv), k + 1));
            float x2 = __uint_as_float(__builtin_amdgcn_readlane(__float_as_uint(hv), k + 2));
            float x3 = __uint_as_float(__builtin_amdgcn_readlane(__float_as_uint(hv), k + 3));
            a0 = fmaf(x0, w[k + 0], a0);
            a1 = fmaf(x1, w[k + 1], a1);
            a2 = fmaf(x2, w[k + 2], a2);
            a3 = fmaf(x3, w[k + 3], a3);
        }
        h0[r * DF + lane] = (a0 + a1) + (a2 + a3);
    }
}

// hout[n] = hin[n] * dinv[n]^2          (hop self-loop term, float4)
__global__ __launch_bounds__(256) void hop_init(const float* __restrict__ hin,
                                                const float* __restrict__ dinv,
                                                float* __restrict__ hout, int n) {
    int i = blockIdx.x * blockDim.x + threadIdx.x;  // over n*16 float4s
    if (i >= n * (DF / 4)) return;
    int r = i >> 4;
    float dv = dinv[r];
    float s = dv * dv;
    float4 v = reinterpret_cast<const float4*>(hin)[i];
    float4 o = {v.x * s, v.y * s, v.z * s, v.w * s};
    reinterpret_cast<float4*>(hout)[i] = o;
}

// hout[n] = hin[n] * dinv[n]^2 + b      (hop-2 self-loop + bias fold)
__global__ __launch_bounds__(256) void hop_init_bias(const float* __restrict__ hin,
                                                     const float* __restrict__ dinv,
                                                     const float* __restrict__ bias,
                                                     float* __restrict__ hout, int n) {
    int i = blockIdx.x * blockDim.x + threadIdx.x;
    if (i >= n * (DF / 4)) return;
    int r = i >> 4, q = i & 15;
    float dv = dinv[r];
    float s = dv * dv;
    float4 v = reinterpret_cast<const float4*>(hin)[i];
    float4 bb = reinterpret_cast<const float4*>(bias)[q];
    float4 o = {fmaf(v.x, s, bb.x), fmaf(v.y, s, bb.y), fmaf(v.z, s, bb.z), fmaf(v.w, s, bb.w)};
    reinterpret_cast<float4*>(hout)[i] = o;
}

// hout[dst[e]] += hin[src[e]] * norm[e]   — 16 threads per edge, float4 gather,
// 4 scalar f32 atomics per thread (device-scope, cross-XCD safe).
__global__ __launch_bounds__(256) void hop_scatter(const int* __restrict__ src,
                                                   const int* __restrict__ dst,
                                                   const float* __restrict__ norm,
                                                   const float* __restrict__ hin,
                                                   float* hout, int ne) {
    int tid = blockIdx.x * blockDim.x + threadIdx.x;
    int e = tid >> 4, q = tid & 15;
    if (e >= ne) return;
    int s = src[e], d = dst[e];
    float nm = norm[e];
    float4 v = reinterpret_cast<const float4*>(hin)[s * (DF / 4) + q];
    float* p = hout + d * DF + q * 4;
    atomicAdd(p + 0, v.x * nm);
    atomicAdd(p + 1, v.y * nm);
    atomicAdd(p + 2, v.z * nm);
    atomicAdd(p + 3, v.w * nm);
}

extern "C" void kernel_launch(void* const* d_in, const int* in_sizes, int n_in,
                              void* d_out, int out_size, void* d_ws, size_t ws_size,
                              hipStream_t stream) {
    const float* x  = (const float*)d_in[0];
    const int*   ei = (const int*)d_in[1];
    const float* Wm = (const float*)d_in[2];
    const float* b  = (const float*)d_in[3];

    const int N = in_sizes[0] / DF;     // 100000
    const int E = in_sizes[1] / 2;      // 1000000
    const int* src = ei;                // edge_index[0]
    const int* dst = ei + E;            // edge_index[1]

    float* dinv = (float*)d_ws;                 // N floats
    float* norm = dinv + N;                     // E floats
    float* h1   = norm + E;                     // N*DF floats
    float* h0   = (float*)d_out;                // reuse output buffer as h0 = x W^T

    const int BT = 256;
    int gN   = (N + BT - 1) / BT;
    int gE   = (E + BT - 1) / BT;
    int gNV  = (N * (DF / 4) + BT - 1) / BT;    // float4-granular over h
    int gES  = (E * 16 + BT - 1) / BT;          // 16 threads / edge

    // degrees -> dinv -> per-edge norm
    deg_init<<<gN, BT, 0, stream>>>(dinv, N);
    deg_scatter<<<gE, BT, 0, stream>>>(dst, dinv, E);
    dinv_k<<<gN, BT, 0, stream>>>(dinv, N);
    norm_k<<<gE, BT, 0, stream>>>(src, dst, dinv, norm, E);

    // h0 = x W^T  (linear first: commutes with propagation)
    gemm_xw<<<1024, BT, 0, stream>>>(x, Wm, h0, N);

    // hop 1: h1 = A_hat h0
    hop_init<<<gNV, BT, 0, stream>>>(h0, dinv, h1, N);
    hop_scatter<<<gES, BT, 0, stream>>>(src, dst, norm, h0, h1, E);

    // hop 2: out = A_hat h1 + b   (bias folded into init)
    hop_init_bias<<<gNV, BT, 0, stream>>>(h1, dinv, b, h0, N);
    hop_scatter<<<gES, BT, 0, stream>>>(src, dst, norm, h1, h0, E);
}

// Round 2
// 314.859 us; speedup vs baseline: 5.8417x; 5.8417x over previous
//
#include <hip/hip_runtime.h>

// SGC: out = A_hat^2 (x W^T) + b,  A_hat = D^-1/2 (A+I) D^-1/2.
// Strategy: GEMM first (commutes with propagation), then two ATOMIC-FREE
// gather hops over a per-call-built CSR (grouped by dst).
// Trick: carry g = D^-1/2 * h between stages so the inner gather loop is an
// unweighted sum:  h'[n] = dinv[n] * (g[n] + sum_{e: dst=n} g[src[e]]).
//   - gemm writes  g0 = dinv .* (x W^T)
//   - hop1 writes  g1 = dinv^2 .* (sum)        (the "g" of h1)
//   - hop2 writes  out = dinv .* (sum) + b
//
// ws layout (4B elems): counts[N] | ofs[N+1] | cursor[N] | bsum[512] |
//                       dinv[N] | ent[E] | g1[N*64]   (~31 MB)

#define DF 64

// ---------------- degree counting ----------------
__global__ __launch_bounds__(256) void zero_counts(int* c, int n) {
    int i = blockIdx.x * blockDim.x + threadIdx.x;
    if (i < n) c[i] = 0;
}

__global__ __launch_bounds__(256) void count_k(const int* __restrict__ dst, int* c, int ne) {
    int e = blockIdx.x * blockDim.x + threadIdx.x;
    if (e < ne) atomicAdd(&c[dst[e]], 1);
}

// ---------------- exclusive scan over counts (3 kernels) ----------------
__global__ __launch_bounds__(256) void scan1(const int* __restrict__ counts, int* __restrict__ ofs,
                                             int* __restrict__ bsum, float* __restrict__ dinv, int n) {
    __shared__ int sm[256];
    int t = threadIdx.x, i = blockIdx.x * 256 + t;
    int c = (i < n) ? counts[i] : 0;
    if (i < n) dinv[i] = rsqrtf((float)(c + 1));  // deg = indeg + self-loop >= 1
    sm[t] = c;
    __syncthreads();
    int v = c;
    for (int off = 1; off < 256; off <<= 1) {
        int tmp = (t >= off) ? sm[t - off] : 0;
        __syncthreads();
        v += tmp;
        sm[t] = v;
        __syncthreads();
    }
    if (i < n) ofs[i] = v - c;               // block-local exclusive
    if (t == 255) bsum[blockIdx.x] = v;      // block total
}

__global__ __launch_bounds__(512) void scan2(int* bsum, int nb) {  // nb <= 512
    __shared__ int sm[512];
    int t = threadIdx.x;
    int c = (t < nb) ? bsum[t] : 0;
    sm[t] = c;
    __syncthreads();
    int v = c;
    for (int off = 1; off < 512; off <<= 1) {
        int tmp = (t >= off) ? sm[t - off] : 0;
        __syncthreads();
        v += tmp;
        sm[t] = v;
        __syncthreads();
    }
    if (t < nb) bsum[t] = v - c;             // exclusive
}

__global__ __launch_bounds__(256) void scan3(int* __restrict__ ofs, int* __restrict__ cursor,
                                             const int* __restrict__ bsum, int n, int ne) {
    int i = blockIdx.x * blockDim.x + threadIdx.x;
    if (i < n) {
        int v = ofs[i] + bsum[i >> 8];
        ofs[i] = v;
        cursor[i] = v;
    }
    if (i == 0) ofs[n] = ne;
}

// ---------------- CSR fill (1M int atomics, order within row arbitrary) ----
__global__ __launch_bounds__(256) void fill_k(const int* __restrict__ src, const int* __restrict__ dst,
                                              int* cursor, int* __restrict__ ent, int ne) {
    int e = blockIdx.x * blockDim.x + threadIdx.x;
    if (e < ne) {
        int pos = atomicAdd(&cursor[dst[e]], 1);
        ent[pos] = src[e];
    }
}

// ---------------- g0 = dinv .* (x W^T) ----------------
// wave per row; lane j holds W[j][:] in 64 regs; x broadcast via readlane.
__global__ __launch_bounds__(256) void gemm_xw(const float* __restrict__ x,
                                               const float* __restrict__ Wm,
                                               const float* __restrict__ dinv,
                                               float* __restrict__ g0, int nrows) {
    int lane = threadIdx.x & 63;
    int wave = (blockIdx.x * blockDim.x + threadIdx.x) >> 6;
    int nwaves = (gridDim.x * blockDim.x) >> 6;

    float w[DF];
#pragma unroll
    for (int k = 0; k < DF; ++k) w[k] = Wm[lane * DF + k];

    for (int r = wave; r < nrows; r += nwaves) {
        float hv = x[r * DF + lane];
        float dv = dinv[r];
        float a0 = 0.f, a1 = 0.f, a2 = 0.f, a3 = 0.f;
#pragma unroll
        for (int k = 0; k < DF; k += 4) {
            float x0 = __uint_as_float(__builtin_amdgcn_readlane(__float_as_uint(hv), k + 0));
            float x1 = __uint_as_float(__builtin_amdgcn_readlane(__float_as_uint(hv), k + 1));
            float x2 = __uint_as_float(__builtin_amdgcn_readlane(__float_as_uint(hv), k + 2));
            float x3 = __uint_as_float(__builtin_amdgcn_readlane(__float_as_uint(hv), k + 3));
            a0 = fmaf(x0, w[k + 0], a0);
            a1 = fmaf(x1, w[k + 1], a1);
            a2 = fmaf(x2, w[k + 2], a2);
            a3 = fmaf(x3, w[k + 3], a3);
        }
        g0[r * DF + lane] = dv * ((a0 + a1) + (a2 + a3));
    }
}

// ---------------- gather hop (atomic-free) ----------------
// One wave per node. MODE 0: out = dinv^2 * acc (produces g of h1).
//                    MODE 1: out = dinv * acc + bias (final output).
template <int MODE>
__global__ __launch_bounds__(256) void gather_k(const int* __restrict__ ofs,
                                                const int* __restrict__ ent,
                                                const float* __restrict__ dinv,
                                                const float* __restrict__ gin,
                                                const float* __restrict__ bias,
                                                float* __restrict__ out, int n) {
    int lane = threadIdx.x & 63;
    int wid = (blockIdx.x * blockDim.x + threadIdx.x) >> 6;
    wid = __builtin_amdgcn_readfirstlane(wid);   // wave-uniform -> scalar loads
    if (wid >= n) return;

    int beg = ofs[wid], end = ofs[wid + 1];
    float dv = dinv[wid];
    float acc0 = gin[wid * DF + lane];  // self-loop term g[n]
    float acc1 = 0.f, acc2 = 0.f, acc3 = 0.f;

    int i = beg;
    for (; i + 3 < end; i += 4) {       // 4 independent chains for latency hiding
        int s0 = ent[i + 0], s1 = ent[i + 1], s2 = ent[i + 2], s3 = ent[i + 3];
        acc0 += gin[s0 * DF + lane];
        acc1 += gin[s1 * DF + lane];
        acc2 += gin[s2 * DF + lane];
        acc3 += gin[s3 * DF + lane];
    }
    for (; i < end; ++i) acc0 += gin[ent[i] * DF + lane];

    float acc = (acc0 + acc1) + (acc2 + acc3);
    if (MODE == 0)
        out[wid * DF + lane] = dv * dv * acc;
    else
        out[wid * DF + lane] = fmaf(dv, acc, bias[lane]);
}

extern "C" void kernel_launch(void* const* d_in, const int* in_sizes, int n_in,
                              void* d_out, int out_size, void* d_ws, size_t ws_size,
                              hipStream_t stream) {
    const float* x  = (const float*)d_in[0];
    const int*   ei = (const int*)d_in[1];
    const float* Wm = (const float*)d_in[2];
    const float* b  = (const float*)d_in[3];

    const int N = in_sizes[0] / DF;   // 100000
    const int E = in_sizes[1] / 2;    // 1000000
    const int* src = ei;
    const int* dst = ei + E;

    int*   counts = (int*)d_ws;             // N
    int*   ofs    = counts + N;             // N+1
    int*   cursor = ofs + N + 1;            // N
    int*   bsum   = cursor + N;             // 512
    float* dinv   = (float*)(bsum + 512);   // N
    int*   ent    = (int*)(dinv + N);       // E
    float* g1     = (float*)(ent + E);      // N*DF
    float* g0     = (float*)d_out;          // reuse output buffer

    const int BT = 256;
    int gN = (N + BT - 1) / BT;             // 391 (also the scan block count, <=512)
    int gE = (E + BT - 1) / BT;
    int gG = (N * DF + BT - 1) / BT;        // one wave per node

    // CSR build + dinv
    zero_counts<<<gN, BT, 0, stream>>>(counts, N);
    count_k<<<gE, BT, 0, stream>>>(dst, counts, E);
    scan1<<<gN, BT, 0, stream>>>(counts, ofs, bsum, dinv, N);
    scan2<<<1, 512, 0, stream>>>(bsum, gN);
    scan3<<<gN, BT, 0, stream>>>(ofs, cursor, bsum, N, E);
    fill_k<<<gE, BT, 0, stream>>>(src, dst, cursor, ent, E);

    // g0 = dinv .* (x W^T)
    gemm_xw<<<1024, BT, 0, stream>>>(x, Wm, dinv, g0, N);

    // hop 1: g1 = dinv^2 .* ((A+I) g0)
    gather_k<0><<<gG, BT, 0, stream>>>(ofs, ent, dinv, g0, nullptr, g1, N);
    // hop 2: out = dinv .* ((A+I) g1) + b
    gather_k<1><<<gG, BT, 0, stream>>>(ofs, ent, dinv, g1, b, g0, N);
}